// Round 1
// baseline (245.350 us; speedup 1.0000x reference)
//
#include <hip/hip_runtime.h>
#include <hip/hip_bf16.h>
#include <math.h>

// Problem constants
constexpr int B = 16;
constexpr int S = 2048;
constexpr int H = 1024;
constexpr int E = 2048;

// ---------------------------------------------------------------------------
// K1: q_proj[b,h] = sum_q query[b,q] * W_q[h,q]   (wave per output)
// ---------------------------------------------------------------------------
__global__ void k_qproj(const float* __restrict__ query,
                        const float* __restrict__ W_q,
                        float* __restrict__ q_proj) {
    int gtid = blockIdx.x * blockDim.x + threadIdx.x;
    int wave = gtid >> 6;
    int lane = threadIdx.x & 63;
    int b = wave / H;
    int h = wave % H;
    const float* qrow = query + b * H;
    const float* wrow = W_q + (size_t)h * H;
    float acc = 0.f;
    #pragma unroll
    for (int q = lane; q < H; q += 64) acc += qrow[q] * wrow[q];
    #pragma unroll
    for (int off = 32; off; off >>= 1) acc += __shfl_down(acc, off, 64);
    if (lane == 0) q_proj[wave] = acc;
}

// ---------------------------------------------------------------------------
// K2: qW[b,h] = sum_h' q_proj[b,h'] * W_bil[h',h]  (thread per h, coalesced)
// ---------------------------------------------------------------------------
__global__ void k_qw(const float* __restrict__ q_proj,
                     const float* __restrict__ W_bil,
                     float* __restrict__ qW) {
    __shared__ float qp[H];
    int b = blockIdx.y;
    int h = blockIdx.x * 256 + threadIdx.x;
    for (int i = threadIdx.x; i < H; i += 256) qp[i] = q_proj[b * H + i];
    __syncthreads();
    float acc = 0.f;
    for (int hp = 0; hp < H; ++hp) acc += qp[hp] * W_bil[(size_t)hp * H + h];
    qW[b * H + h] = acc;
}

// ---------------------------------------------------------------------------
// K3: u[b,e] = sum_h qW[b,h] * W_enc[h,e]   (thread per e, coalesced)
// ---------------------------------------------------------------------------
__global__ void k_u(const float* __restrict__ qW,
                    const float* __restrict__ W_enc,
                    float* __restrict__ u) {
    __shared__ float qw[H];
    int b = blockIdx.y;
    int e = blockIdx.x * 256 + threadIdx.x;
    for (int i = threadIdx.x; i < H; i += 256) qw[i] = qW[b * H + i];
    __syncthreads();
    float acc = 0.f;
    for (int h = 0; h < H; ++h) acc += qw[h] * W_enc[(size_t)h * E + e];
    u[b * E + e] = acc;
}

// ---------------------------------------------------------------------------
// K4: scores[b,s] = mask ? dot(u[b,:], value[b,s,:]) : -inf
// One wave per s-row; float4 loads (1 KiB/wave-instr); u[b] staged in LDS.
// Writes into the alphas region of d_out (softmax then runs in-place).
// ---------------------------------------------------------------------------
__global__ void k_scores(const float* __restrict__ u,
                         const float* __restrict__ value,
                         const int* __restrict__ mask,
                         float* __restrict__ scores) {
    __shared__ float ub[E];
    int b = blockIdx.y;
    for (int i = threadIdx.x; i < E; i += 256) ub[i] = u[b * E + i];
    __syncthreads();
    int w = threadIdx.x >> 6;
    int lane = threadIdx.x & 63;
    int s = blockIdx.x * 4 + w;
    const float4* vrow = (const float4*)(value + ((size_t)(b * S + s)) * E);
    const float4* u4 = (const float4*)ub;
    float acc = 0.f;
    #pragma unroll
    for (int i = 0; i < E / 256; ++i) {  // 8 iters of 64 lanes * float4
        float4 vv = vrow[i * 64 + lane];
        float4 uu = u4[i * 64 + lane];
        acc += vv.x * uu.x + vv.y * uu.y + vv.z * uu.z + vv.w * uu.w;
    }
    #pragma unroll
    for (int off = 32; off; off >>= 1) acc += __shfl_down(acc, off, 64);
    if (lane == 0) {
        scores[b * S + s] = mask[b * S + s] ? acc : -INFINITY;
    }
}

// ---------------------------------------------------------------------------
// K5: in-place softmax over alphas[b, :]   (one block per b)
// ---------------------------------------------------------------------------
__global__ void k_softmax(float* __restrict__ alphas) {
    __shared__ float sc[S];
    __shared__ float red[256];
    int b = blockIdx.x;
    float* a = alphas + b * S;
    float m = -INFINITY;
    for (int s = threadIdx.x; s < S; s += 256) {
        float v = a[s];
        sc[s] = v;
        m = fmaxf(m, v);
    }
    red[threadIdx.x] = m;
    __syncthreads();
    for (int off = 128; off; off >>= 1) {
        if (threadIdx.x < off)
            red[threadIdx.x] = fmaxf(red[threadIdx.x], red[threadIdx.x + off]);
        __syncthreads();
    }
    m = red[0];
    __syncthreads();
    float l = 0.f;
    for (int s = threadIdx.x; s < S; s += 256) {
        float p = expf(sc[s] - m);
        sc[s] = p;
        l += p;
    }
    red[threadIdx.x] = l;
    __syncthreads();
    for (int off = 128; off; off >>= 1) {
        if (threadIdx.x < off)
            red[threadIdx.x] += red[threadIdx.x + off];
        __syncthreads();
    }
    float inv = 1.f / red[0];
    for (int s = threadIdx.x; s < S; s += 256) a[s] = sc[s] * inv;
}

// ---------------------------------------------------------------------------
// K6: context[b,e] = sum_s alphas[b,s] * value[b,s,e]
// Block-uniform skip of negligible alphas (softmax is extremely peaked:
// score sigma ~= 32 -> nearly all rows underflow). Error bound:
// 2048 * 1e-8 * max|v| ~= 1e-4 << 7.75e-2 threshold.
// ---------------------------------------------------------------------------
__global__ void k_context(const float* __restrict__ alphas,
                          const float* __restrict__ value,
                          float* __restrict__ context) {
    __shared__ float al[S];
    int b = blockIdx.y;
    int e4 = blockIdx.x * 256 + threadIdx.x;  // float4 column index
    for (int i = threadIdx.x; i < S; i += 256) al[i] = alphas[b * S + i];
    __syncthreads();
    float4 acc = {0.f, 0.f, 0.f, 0.f};
    for (int s = 0; s < S; ++s) {
        float a = al[s];
        if (a > 1e-8f) {  // uniform across block -> no divergence
            float4 v = ((const float4*)(value + ((size_t)(b * S + s)) * E))[e4];
            acc.x += a * v.x;
            acc.y += a * v.y;
            acc.z += a * v.z;
            acc.w += a * v.w;
        }
    }
    ((float4*)(context + b * E))[e4] = acc;
}

// ---------------------------------------------------------------------------
extern "C" void kernel_launch(void* const* d_in, const int* in_sizes, int n_in,
                              void* d_out, int out_size, void* d_ws, size_t ws_size,
                              hipStream_t stream) {
    const float* query = (const float*)d_in[0];   // [B,1,H]
    const float* value = (const float*)d_in[1];   // [B,S,E]
    const int*   mask  = (const int*)d_in[2];     // [B,1,S]
    const float* W_enc = (const float*)d_in[3];   // [H,E]
    const float* W_q   = (const float*)d_in[4];   // [H,H]
    const float* W_bil = (const float*)d_in[5];   // [H,H]

    float* out = (float*)d_out;
    float* context = out;          // [B,1,E] = B*E floats
    float* alphas  = out + B * E;  // [B,1,S] = B*S floats

    float* ws = (float*)d_ws;
    float* q_proj = ws;                // B*H
    float* qW     = ws + B * H;        // B*H
    float* u      = ws + 2 * B * H;    // B*E

    // Small matvec chain: q_proj -> qW -> u
    k_qproj<<<dim3(B * H / 4), 256, 0, stream>>>(query, W_q, q_proj);
    k_qw<<<dim3(H / 256, B), 256, 0, stream>>>(q_proj, W_bil, qW);
    k_u<<<dim3(E / 256, B), 256, 0, stream>>>(qW, W_enc, u);

    // Scores (the 268 MB HBM stream), softmax in-place, weighted context
    k_scores<<<dim3(S / 4, B), 256, 0, stream>>>(u, value, mask, alphas);
    k_softmax<<<dim3(B), 256, 0, stream>>>(alphas);
    k_context<<<dim3(E / 1024, B), 256, 0, stream>>>(alphas, value, context);
}

// Round 3
// 185.991 us; speedup vs baseline: 1.3191x; 1.3191x over previous
//
#include <hip/hip_runtime.h>
#include <hip/hip_bf16.h>
#include <math.h>

// Problem constants
constexpr int B = 16;
constexpr int S = 2048;
constexpr int H = 1024;
constexpr int E = 2048;

constexpr int KSPL = 16;           // split-K factor for the matvec chain
constexpr int QW_CHUNK = H / KSPL; // 64 rows per block

// ---------------------------------------------------------------------------
// K1: q_proj[b,h] = sum_q query[b,q] * W_q[h,q]   (wave per output)
// Blocks >= B*H/4 instead zero the atomic-target region (qW, u) for this call.
// ---------------------------------------------------------------------------
__global__ void k_qproj_zero(const float* __restrict__ query,
                             const float* __restrict__ W_q,
                             float* __restrict__ q_proj,
                             float* __restrict__ zbase /* qW..u, 48K floats */) {
    if (blockIdx.x >= (B * H / 4)) {
        int zb = blockIdx.x - B * H / 4;              // 0..47
        ((float4*)zbase)[zb * 256 + threadIdx.x] = make_float4(0.f, 0.f, 0.f, 0.f);
        return;
    }
    int gtid = blockIdx.x * blockDim.x + threadIdx.x;
    int wave = gtid >> 6;
    int lane = threadIdx.x & 63;
    int b = wave / H;
    int h = wave % H;
    const float* qrow = query + b * H;
    const float* wrow = W_q + (size_t)h * H;
    float acc = 0.f;
    #pragma unroll
    for (int q = lane; q < H; q += 64) acc += qrow[q] * wrow[q];
    #pragma unroll
    for (int off = 32; off; off >>= 1) acc += __shfl_down(acc, off, 64);
    if (lane == 0) q_proj[wave] = acc;
}

// ---------------------------------------------------------------------------
// K2: qW[b,h] += sum_{hp in chunk} q_proj[b,hp] * W_bil[hp,h]
// grid (H/256, B/4, KSPL); 4 batches per thread; split-K partials via atomicAdd.
// ---------------------------------------------------------------------------
__global__ void k_qw(const float* __restrict__ q_proj,
                     const float* __restrict__ W_bil,
                     float* __restrict__ qW) {
    __shared__ float4 qp4[QW_CHUNK];
    int h = blockIdx.x * 256 + threadIdx.x;
    int b0 = blockIdx.y * 4;
    int hp0 = blockIdx.z * QW_CHUNK;
    if (threadIdx.x < QW_CHUNK) {
        int hp = hp0 + threadIdx.x;
        qp4[threadIdx.x] = make_float4(q_proj[(b0 + 0) * H + hp],
                                       q_proj[(b0 + 1) * H + hp],
                                       q_proj[(b0 + 2) * H + hp],
                                       q_proj[(b0 + 3) * H + hp]);
    }
    __syncthreads();
    float4 acc = {0.f, 0.f, 0.f, 0.f};
    #pragma unroll 8
    for (int hp = 0; hp < QW_CHUNK; ++hp) {
        float w = W_bil[(size_t)(hp0 + hp) * H + h];
        float4 q = qp4[hp];
        acc.x += q.x * w; acc.y += q.y * w; acc.z += q.z * w; acc.w += q.w * w;
    }
    atomicAdd(&qW[(b0 + 0) * H + h], acc.x);
    atomicAdd(&qW[(b0 + 1) * H + h], acc.y);
    atomicAdd(&qW[(b0 + 2) * H + h], acc.z);
    atomicAdd(&qW[(b0 + 3) * H + h], acc.w);
}

// ---------------------------------------------------------------------------
// K3: u[b,e] += sum_{h in chunk} qW[b,h] * W_enc[h,e]   (same structure)
// ---------------------------------------------------------------------------
__global__ void k_u(const float* __restrict__ qW,
                    const float* __restrict__ W_enc,
                    float* __restrict__ u) {
    __shared__ float4 qp4[QW_CHUNK];
    int e = blockIdx.x * 256 + threadIdx.x;
    int b0 = blockIdx.y * 4;
    int h0 = blockIdx.z * QW_CHUNK;
    if (threadIdx.x < QW_CHUNK) {
        int h = h0 + threadIdx.x;
        qp4[threadIdx.x] = make_float4(qW[(b0 + 0) * H + h],
                                       qW[(b0 + 1) * H + h],
                                       qW[(b0 + 2) * H + h],
                                       qW[(b0 + 3) * H + h]);
    }
    __syncthreads();
    float4 acc = {0.f, 0.f, 0.f, 0.f};
    #pragma unroll 8
    for (int h = 0; h < QW_CHUNK; ++h) {
        float w = W_enc[(size_t)(h0 + h) * E + e];
        float4 q = qp4[h];
        acc.x += q.x * w; acc.y += q.y * w; acc.z += q.z * w; acc.w += q.w * w;
    }
    atomicAdd(&u[(b0 + 0) * E + e], acc.x);
    atomicAdd(&u[(b0 + 1) * E + e], acc.y);
    atomicAdd(&u[(b0 + 2) * E + e], acc.z);
    atomicAdd(&u[(b0 + 3) * E + e], acc.w);
}

// ---------------------------------------------------------------------------
// K4: scores[b,s] = mask ? dot(u[b,:], value[b,s,:]) : -inf
// One wave per s-row; float4 loads; u[b] staged in LDS. The 268 MB HBM stream.
// ---------------------------------------------------------------------------
__global__ void k_scores(const float* __restrict__ u,
                         const float* __restrict__ value,
                         const int* __restrict__ mask,
                         float* __restrict__ scores) {
    __shared__ float ub[E];
    int b = blockIdx.y;
    for (int i = threadIdx.x; i < E; i += 256) ub[i] = u[b * E + i];
    __syncthreads();
    int w = threadIdx.x >> 6;
    int lane = threadIdx.x & 63;
    int s = blockIdx.x * 4 + w;
    const float4* vrow = (const float4*)(value + ((size_t)(b * S + s)) * E);
    const float4* u4 = (const float4*)ub;
    float acc = 0.f;
    #pragma unroll
    for (int i = 0; i < E / 256; ++i) {  // 8 iters of 64 lanes * float4
        float4 vv = vrow[i * 64 + lane];
        float4 uu = u4[i * 64 + lane];
        acc += vv.x * uu.x + vv.y * uu.y + vv.z * uu.z + vv.w * uu.w;
    }
    #pragma unroll
    for (int off = 32; off; off >>= 1) acc += __shfl_down(acc, off, 64);
    if (lane == 0) {
        scores[b * S + s] = mask[b * S + s] ? acc : -INFINITY;
    }
}

// ---------------------------------------------------------------------------
// K5: in-place softmax over alphas[b, :]   (one block per b)
// ---------------------------------------------------------------------------
__global__ void k_softmax(float* __restrict__ alphas) {
    __shared__ float sc[S];
    __shared__ float red[256];
    int b = blockIdx.x;
    float* a = alphas + b * S;
    float m = -INFINITY;
    for (int s = threadIdx.x; s < S; s += 256) {
        float v = a[s];
        sc[s] = v;
        m = fmaxf(m, v);
    }
    red[threadIdx.x] = m;
    __syncthreads();
    for (int off = 128; off; off >>= 1) {
        if (threadIdx.x < off)
            red[threadIdx.x] = fmaxf(red[threadIdx.x], red[threadIdx.x + off]);
        __syncthreads();
    }
    m = red[0];
    __syncthreads();
    float l = 0.f;
    for (int s = threadIdx.x; s < S; s += 256) {
        float p = expf(sc[s] - m);
        sc[s] = p;
        l += p;
    }
    red[threadIdx.x] = l;
    __syncthreads();
    for (int off = 128; off; off >>= 1) {
        if (threadIdx.x < off)
            red[threadIdx.x] += red[threadIdx.x + off];
        __syncthreads();
    }
    float inv = 1.f / red[0];
    for (int s = threadIdx.x; s < S; s += 256) a[s] = sc[s] * inv;
}

// ---------------------------------------------------------------------------
// K6: context[b,e] = sum_s alphas[b,s] * value[b,s,e]
// Block-uniform skip of negligible alphas (softmax is extremely peaked:
// score sigma ~= 32 -> nearly all rows underflow). Error bound:
// 2048 * 1e-8 * max|v| ~= 1e-4 << 7.75e-2 threshold.
// ---------------------------------------------------------------------------
__global__ void k_context(const float* __restrict__ alphas,
                          const float* __restrict__ value,
                          float* __restrict__ context) {
    __shared__ float al[S];
    int b = blockIdx.y;
    int e4 = blockIdx.x * 256 + threadIdx.x;  // float4 column index
    for (int i = threadIdx.x; i < S; i += 256) al[i] = alphas[b * S + i];
    __syncthreads();
    float4 acc = {0.f, 0.f, 0.f, 0.f};
    for (int s = 0; s < S; ++s) {
        float a = al[s];
        if (a > 1e-8f) {  // uniform across block -> no divergence
            float4 v = ((const float4*)(value + ((size_t)(b * S + s)) * E))[e4];
            acc.x += a * v.x;
            acc.y += a * v.y;
            acc.z += a * v.z;
            acc.w += a * v.w;
        }
    }
    ((float4*)(context + b * E))[e4] = acc;
}

// ---------------------------------------------------------------------------
extern "C" void kernel_launch(void* const* d_in, const int* in_sizes, int n_in,
                              void* d_out, int out_size, void* d_ws, size_t ws_size,
                              hipStream_t stream) {
    const float* query = (const float*)d_in[0];   // [B,1,H]
    const float* value = (const float*)d_in[1];   // [B,S,E]
    const int*   mask  = (const int*)d_in[2];     // [B,1,S]
    const float* W_enc = (const float*)d_in[3];   // [H,E]
    const float* W_q   = (const float*)d_in[4];   // [H,H]
    const float* W_bil = (const float*)d_in[5];   // [H,H]

    float* out = (float*)d_out;
    float* context = out;          // [B,1,E] = B*E floats
    float* alphas  = out + B * E;  // [B,1,S] = B*S floats

    float* ws = (float*)d_ws;
    float* q_proj = ws;                // B*H
    float* qW     = ws + B * H;        // B*H   (atomic target, zeroed in K1)
    float* u      = ws + 2 * B * H;    // B*E   (atomic target, zeroed in K1)

    // K1: q_proj + zero the 48K-float atomic region (qW,u) in extra blocks
    k_qproj_zero<<<dim3(B * H / 4 + 48), 256, 0, stream>>>(query, W_q, q_proj, qW);

    // K2,K3: split-K batched matvecs with atomic partial sums
    k_qw<<<dim3(H / 256, B / 4, KSPL), 256, 0, stream>>>(q_proj, W_bil, qW);
    k_u <<<dim3(E / 256, B / 4, KSPL), 256, 0, stream>>>(qW, W_enc, u);

    // Scores (the 268 MB HBM stream), softmax in-place, weighted context
    k_scores<<<dim3(S / 4, B), 256, 0, stream>>>(u, value, mask, alphas);
    k_softmax<<<dim3(B), 256, 0, stream>>>(alphas);
    k_context<<<dim3(E / 1024, B), 256, 0, stream>>>(alphas, value, context);
}